// Round 1
// 93.713 us; speedup vs baseline: 1.0064x; 1.0064x over previous
//
#include <hip/hip_runtime.h>
#include <math.h>

#define NN 320
#define DD 256

// Packed weight rows: code(TABLE[cidx][v]) at bit 2*v; code: mapped 1->2,
// 2->1, 0->0; weight = code*0.5. v0 is 0 in every row.
__device__ __constant__ unsigned int c_PACK[7] =
    {0x2294u, 0x1554u, 0x1254u, 0x1554u, 0x1654u, 0x1154u, 0x2294u};

// Prep: blocks 0..19 transpose F(320x256) -> FT4 (float4-packed, [d4*NN+j]);
// blocks 20..24 compute meta[j] = {t, rlt, rle, pos|ev<<16} for 64 j each;
// block 25 zeroes the accumulators + ticket.
__global__ __launch_bounds__(256) void prep_kernel(
    const float* __restrict__ F, const float* __restrict__ yt,
    const int* __restrict__ ye, float4* __restrict__ FT4,
    float4* __restrict__ meta, float* __restrict__ acc) {
    __shared__ float sh[64 * 65];
    __shared__ int rr[3][4][64];
    const int b = blockIdx.x;
    const int tid = threadIdx.x;
    if (b < 20) {
        float (*tile)[65] = (float(*)[65])sh;
        const int I = b % 5;            // i-tile 0..4
        const int J = b / 5;            // d-tile 0..3 (64 dims each)
        const int lane = tid & 63;
        const int quad = tid >> 6;
#pragma unroll
        for (int r0 = 0; r0 < 64; r0 += 4) {
            const int r = r0 + quad;    // local i
            tile[r][lane] = F[(I * 64 + r) * DD + J * 64 + lane];
        }
        __syncthreads();
#pragma unroll
        for (int q = 0; q < 16; q += 4) {
            const int d4 = q + quad;    // local d4 (0..15)
            float4 v = make_float4(tile[lane][d4 * 4 + 0], tile[lane][d4 * 4 + 1],
                                   tile[lane][d4 * 4 + 2], tile[lane][d4 * 4 + 3]);
            FT4[(J * 16 + d4) * NN + I * 64 + lane] = v;   // coalesced in j
        }
    } else if (b < 25) {
        float* s_t = sh;
        for (int l = tid; l < NN; l += 256) s_t[l] = yt[l];
        __syncthreads();
        const int jj = tid & 63;        // which j in this block's chunk
        const int q  = tid >> 6;        // quarter of the l-range
        const int j  = (b - 20) * 64 + jj;
        const float tj = s_t[j];
        int lt = 0, le = 0, pos = 0;
        const int l0 = q * 80;
        for (int l = l0; l < l0 + 80; ++l) {
            const float tl = s_t[l];
            lt  += (tl < tj);
            le  += (tl <= tj);
            pos += (tl < tj) || (tl == tj && l < j);   // tie-break by index
        }
        rr[0][q][jj] = lt; rr[1][q][jj] = le; rr[2][q][jj] = pos;
        __syncthreads();
        if (q == 0) {
#pragma unroll
            for (int w = 1; w < 4; ++w) {
                lt += rr[0][w][jj]; le += rr[1][w][jj]; pos += rr[2][w][jj];
            }
            meta[j] = make_float4(tj, __int_as_float(lt), __int_as_float(le),
                                  __int_as_float(pos | (ye[j] << 16)));
        }
    } else {
        // zero accL[NN], accN[NN], ticket (float 0.0f == bit pattern 0)
        for (int t = tid; t < 2 * NN + 1; t += 256) acc[t] = 0.f;
    }
}

// Fused: block i computes row i's logits + class prefix sums (in LDS only),
// then thread a computes the (anchor=a, row=i) contribution from the
// LDS-resident prefixes and accumulates into accL/accN via atomics.
// Last block (ticket) performs the final reduction.
__global__ __launch_bounds__(NN) void fused_kernel(
    const float* __restrict__ F, const float4* __restrict__ FT4,
    const float4* __restrict__ meta, float* __restrict__ acc,
    float* __restrict__ out) {
    __shared__ __align__(16) float fi[DD];
    __shared__ float S0[NN + 1];
    __shared__ float S1[NN + 1];
    __shared__ float w0[5], w1[5];
    __shared__ float4 smi;
    __shared__ int s_done;

    float* __restrict__ accL = acc;
    float* __restrict__ accN = acc + NN;
    unsigned* ticket = (unsigned*)(acc + 2 * NN);

    const int i = blockIdx.x;
    const int j = threadIdx.x;
    const int wave = j >> 6, lane = j & 63;

    if (j < DD) fi[j] = F[i * DD + j];
    if (j == 0) smi = meta[i];
    const float4 mj = meta[j];          // coalesced; reused as anchor meta below
    __syncthreads();

    // ---- distances: row i vs all j ----
    const float4* __restrict__ fi4 = (const float4*)fi;
    float a0 = 0.f, a1 = 0.f, a2 = 0.f, a3 = 0.f;
#pragma unroll 8
    for (int d4 = 0; d4 < DD / 4; ++d4) {
        const float4 f4 = fi4[d4];                // LDS broadcast
        const float4 g4 = FT4[d4 * NN + j];       // global dwordx4, coalesced
        const float u0 = f4.x - g4.x, u1 = f4.y - g4.y;
        const float u2 = f4.z - g4.z, u3 = f4.w - g4.w;
        a0 = fmaf(u0, u0, a0);
        a1 = fmaf(u1, u1, a1);
        a2 = fmaf(u2, u2, a2);
        a3 = fmaf(u3, u3, a3);
    }
    const float d2 = (a0 + a1) + (a2 + a3);
    const float nrm = (d2 > 0.f) ? sqrtf(d2) : 0.f;
    const float lg = -0.5f * nrm;                 // -norm/TEMP, TEMP=2
    const float e = expf(lg);

    // ---- scatter into sorted-t order, split by event class ----
    const int pej = __float_as_int(mj.w);
    const int pos = pej & 0xFFFF;
    const int evj = pej >> 16;
    S0[pos] = evj ? 0.f : e;
    S1[pos] = evj ? e : 0.f;
    __syncthreads();

    // ---- scan (wave shfl_up + cross-wave fixup); element at sorted idx j ----
    float v0 = S0[j], v1 = S1[j];
#pragma unroll
    for (int off = 1; off < 64; off <<= 1) {
        const float n0 = __shfl_up(v0, off);
        const float n1 = __shfl_up(v1, off);
        if (lane >= off) { v0 += n0; v1 += n1; }
    }
    if (lane == 63) { w0[wave] = v0; w1[wave] = v1; }
    __syncthreads();                    // also fences the S0/S1 reads above
    float p0 = 0.f, p1 = 0.f;
#pragma unroll
    for (int w = 0; w < 4; ++w) {
        if (wave > w) { p0 += w0[w]; p1 += w1[w]; }
    }
    v0 += p0; v1 += p1;
    // exclusive prefix: S[x] = sum_{idx<x}; S[NN] = total
    S0[j + 1] = v0; S1[j + 1] = v1;
    if (j == 0) { S0[0] = 0.f; S1[0] = 0.f; }
    __syncthreads();

    // ---- anchor contribution for pair (anchor a=j, row=i) ----
    const float4 mi = smi;              // uniform row meta
    const float ti = mi.x;
    const int rlt_i = __float_as_int(mi.y), rle_i = __float_as_int(mi.z);
    const int evi   = __float_as_int(mi.w) >> 16;
    const float ta = mj.x;
    const int rlt_a = __float_as_int(mj.y), rle_a = __float_as_int(mj.z);
    const int eva   = evj;

    const int sgn = (ti > ta) ? 1 : ((ti < ta) ? -1 : 0);
    const unsigned pack = c_PACK[3 + sgn * (evi + 2 * eva)];
    const int rlo = min(rlt_i, rlt_a);
    const int rhi = max(rle_i, rle_a);

    const float q0lo = S0[rlo], q0hi = S0[rhi], q0a = S0[rlt_a], q0b = S0[rle_a], t0 = S0[NN];
    const float q1lo = S1[rlo], q1hi = S1[rhi], q1a = S1[rlt_a], q1b = S1[rle_a], t1 = S1[NN];

    const float LO0 = q0lo, HI0 = t0 - q0hi, MI0 = q0hi - q0lo - (q0b - q0a);
    const float LO1 = q1lo, HI1 = t1 - q1hi, MI1 = q1hi - q1lo - (q1b - q1a);

    const float c1 = (float)((pack >> 2) & 3u),  c2 = (float)((pack >> 4) & 3u);
    const float c3 = (float)((pack >> 6) & 3u),  c4 = (float)((pack >> 8) & 3u);
    const float c5 = (float)((pack >> 10) & 3u), c6 = (float)((pack >> 12) & 3u);

    float dx = c1 * LO0 + c2 * MI0 + c3 * HI0 + c4 * LO1 + c5 * MI1 + c6 * HI1; // 2*denom
    if (ti != ta) dx -= (float)((pack >> (2 * (2 + 3 * evi))) & 3u);  // remove j==i term

    if (i != j && dx > 0.f) {
        // lg == L[i][a] == L[a][i] (symmetric); contributes to anchor a
        atomicAdd(&accL[j], lg - logf(0.5f * dx));
        atomicAdd(&accN[j], 1.f);
    }

    // ---- last-block finalize (threadfence-reduction pattern) ----
    __threadfence();
    __syncthreads();
    if (j == 0) {
        const unsigned old = atomicAdd(ticket, 1u);
        s_done = (old == NN - 1);
    }
    __syncthreads();
    if (!s_done) return;
    __threadfence();                    // acquire: see all blocks' atomics

    const float nj = accN[j];
    float lossj = (nj > 0.f) ? (-accL[j] / nj) : 0.f;
    float hasj  = (nj > 0.f) ? 1.f : 0.f;
#pragma unroll
    for (int off = 32; off > 0; off >>= 1) {
        lossj += __shfl_down(lossj, off);
        hasj  += __shfl_down(hasj, off);
    }
    if (lane == 0) { w0[wave] = lossj; w1[wave] = hasj; }
    __syncthreads();
    if (j == 0) {
        float tl = 0.f, th = 0.f;
#pragma unroll
        for (int w = 0; w < 5; ++w) { tl += w0[w]; th += w1[w]; }
        out[0] = tl / th;
    }
}

extern "C" void kernel_launch(void* const* d_in, const int* in_sizes, int n_in,
                              void* d_out, int out_size, void* d_ws, size_t ws_size,
                              hipStream_t stream) {
    const float* F  = (const float*)d_in[0];   // features (320,256) f32
    const float* yt = (const float*)d_in[1];   // y_times (320,) f32
    const int*   ye = (const int*)d_in[2];     // y_events (320,) i32
    float* out = (float*)d_out;
    float* ws  = (float*)d_ws;

    float4* meta = (float4*)ws;                        // 320 float4 (16B-aligned)
    float4* FT4  = (float4*)(ws + 4 * NN);             // 64*320 float4
    float*  acc  = ws + 4 * NN + 4 * (DD / 4) * NN;    // accL[320], accN[320], ticket

    prep_kernel<<<26, 256, 0, stream>>>(F, yt, ye, FT4, meta, acc);
    fused_kernel<<<NN, NN, 0, stream>>>(F, FT4, meta, acc, out);
}

// Round 2
// 81.899 us; speedup vs baseline: 1.1516x; 1.1442x over previous
//
#include <hip/hip_runtime.h>
#include <math.h>

#define NN 320
#define DD 256

// Packed weight rows: code(TABLE[cidx][v]) at bit 2*v; code: mapped 1->2,
// 2->1, 0->0; weight = code*0.5. v0 is 0 in every row.
__device__ __constant__ unsigned int c_PACK[7] =
    {0x2294u, 0x1554u, 0x1254u, 0x1554u, 0x1654u, 0x1154u, 0x2294u};

// Prep: blocks 0..19 transpose F(320x256) -> FT4 (float4-packed, [d4*NN+j]);
// blocks 20..24 compute meta[j] = {t, rlt, rle, pos|ev<<16} for 64 j each;
// block 25 zeroes the accumulators + ticket.
__global__ __launch_bounds__(256) void prep_kernel(
    const float* __restrict__ F, const float* __restrict__ yt,
    const int* __restrict__ ye, float4* __restrict__ FT4,
    float4* __restrict__ meta, float* __restrict__ acc) {
    __shared__ float sh[64 * 65];
    __shared__ int rr[3][4][64];
    const int b = blockIdx.x;
    const int tid = threadIdx.x;
    if (b < 20) {
        float (*tile)[65] = (float(*)[65])sh;
        const int I = b % 5;            // i-tile 0..4
        const int J = b / 5;            // d-tile 0..3 (64 dims each)
        const int lane = tid & 63;
        const int quad = tid >> 6;
#pragma unroll
        for (int r0 = 0; r0 < 64; r0 += 4) {
            const int r = r0 + quad;    // local i
            tile[r][lane] = F[(I * 64 + r) * DD + J * 64 + lane];
        }
        __syncthreads();
#pragma unroll
        for (int q = 0; q < 16; q += 4) {
            const int d4 = q + quad;    // local d4 (0..15)
            float4 v = make_float4(tile[lane][d4 * 4 + 0], tile[lane][d4 * 4 + 1],
                                   tile[lane][d4 * 4 + 2], tile[lane][d4 * 4 + 3]);
            FT4[(J * 16 + d4) * NN + I * 64 + lane] = v;   // coalesced in j
        }
    } else if (b < 25) {
        float* s_t = sh;
        for (int l = tid; l < NN; l += 256) s_t[l] = yt[l];
        __syncthreads();
        const int jj = tid & 63;        // which j in this block's chunk
        const int q  = tid >> 6;        // quarter of the l-range
        const int j  = (b - 20) * 64 + jj;
        const float tj = s_t[j];
        int lt = 0, le = 0, pos = 0;
        const int l0 = q * 80;
        for (int l = l0; l < l0 + 80; ++l) {
            const float tl = s_t[l];
            lt  += (tl < tj);
            le  += (tl <= tj);
            pos += (tl < tj) || (tl == tj && l < j);   // tie-break by index
        }
        rr[0][q][jj] = lt; rr[1][q][jj] = le; rr[2][q][jj] = pos;
        __syncthreads();
        if (q == 0) {
#pragma unroll
            for (int w = 1; w < 4; ++w) {
                lt += rr[0][w][jj]; le += rr[1][w][jj]; pos += rr[2][w][jj];
            }
            meta[j] = make_float4(tj, __int_as_float(lt), __int_as_float(le),
                                  __int_as_float(pos | (ye[j] << 16)));
        }
    } else {
        // zero accL[NN], accN[NN], ticket (float 0.0f == bit pattern 0)
        for (int t = tid; t < 2 * NN + 1; t += 256) acc[t] = 0.f;
    }
}

// Fused, 2 rows per block: block b computes rows i0=2b, i1=2b+1.
// One FT4 stream feeds both rows' distances; one scan pass produces both
// rows' class prefixes; both rows' anchor contributions are combined in
// registers before a single atomic pair per thread.
// Last block (ticket) performs the final reduction.
__global__ __launch_bounds__(NN) void fused_kernel(
    const float* __restrict__ F, const float4* __restrict__ FT4,
    const float4* __restrict__ meta, float* __restrict__ acc,
    float* __restrict__ out) {
    __shared__ __align__(16) float fiA[DD];
    __shared__ __align__(16) float fiB[DD];
    __shared__ float S0A[NN + 1];
    __shared__ float S1A[NN + 1];
    __shared__ float S0B[NN + 1];
    __shared__ float S1B[NN + 1];
    __shared__ float wv[4][5];
    __shared__ float4 smiA, smiB;
    __shared__ int s_done;

    float* __restrict__ accL = acc;
    float* __restrict__ accN = acc + NN;
    unsigned* ticket = (unsigned*)(acc + 2 * NN);

    const int i0 = blockIdx.x * 2;
    const int i1 = i0 + 1;
    const int j = threadIdx.x;
    const int wave = j >> 6, lane = j & 63;

    if (j < DD) {
        fiA[j] = F[i0 * DD + j];
        fiB[j] = F[i1 * DD + j];
    }
    if (j == 0) smiA = meta[i0];
    if (j == 1) smiB = meta[i1];
    const float4 mj = meta[j];          // coalesced; anchor meta below
    __syncthreads();

    // ---- distances: rows i0,i1 vs all j (one FT4 stream, two accumulations)
    const float4* __restrict__ fA4 = (const float4*)fiA;
    const float4* __restrict__ fB4 = (const float4*)fiB;
    float aA0 = 0.f, aA1 = 0.f, aA2 = 0.f, aA3 = 0.f;
    float aB0 = 0.f, aB1 = 0.f, aB2 = 0.f, aB3 = 0.f;
#pragma unroll 8
    for (int d4 = 0; d4 < DD / 4; ++d4) {
        const float4 g4 = FT4[d4 * NN + j];       // global dwordx4, coalesced
        const float4 fA = fA4[d4];                // LDS broadcast
        const float4 fB = fB4[d4];
        float u;
        u = fA.x - g4.x; aA0 = fmaf(u, u, aA0);
        u = fA.y - g4.y; aA1 = fmaf(u, u, aA1);
        u = fA.z - g4.z; aA2 = fmaf(u, u, aA2);
        u = fA.w - g4.w; aA3 = fmaf(u, u, aA3);
        u = fB.x - g4.x; aB0 = fmaf(u, u, aB0);
        u = fB.y - g4.y; aB1 = fmaf(u, u, aB1);
        u = fB.z - g4.z; aB2 = fmaf(u, u, aB2);
        u = fB.w - g4.w; aB3 = fmaf(u, u, aB3);
    }
    const float d2A = (aA0 + aA1) + (aA2 + aA3);
    const float d2B = (aB0 + aB1) + (aB2 + aB3);
    const float lgA = -0.5f * ((d2A > 0.f) ? sqrtf(d2A) : 0.f);  // -norm/TEMP
    const float lgB = -0.5f * ((d2B > 0.f) ? sqrtf(d2B) : 0.f);
    const float eA = expf(lgA);
    const float eB = expf(lgB);

    // ---- scatter into sorted-t order, split by event class ----
    const int pej = __float_as_int(mj.w);
    const int pos = pej & 0xFFFF;
    const int evj = pej >> 16;
    S0A[pos] = evj ? 0.f : eA;
    S1A[pos] = evj ? eA : 0.f;
    S0B[pos] = evj ? 0.f : eB;
    S1B[pos] = evj ? eB : 0.f;
    __syncthreads();

    // ---- scan (wave shfl_up + cross-wave fixup), 4 sequences at once ----
    float vA0 = S0A[j], vA1 = S1A[j], vB0 = S0B[j], vB1 = S1B[j];
#pragma unroll
    for (int off = 1; off < 64; off <<= 1) {
        const float nA0 = __shfl_up(vA0, off);
        const float nA1 = __shfl_up(vA1, off);
        const float nB0 = __shfl_up(vB0, off);
        const float nB1 = __shfl_up(vB1, off);
        if (lane >= off) { vA0 += nA0; vA1 += nA1; vB0 += nB0; vB1 += nB1; }
    }
    if (lane == 63) {
        wv[0][wave] = vA0; wv[1][wave] = vA1;
        wv[2][wave] = vB0; wv[3][wave] = vB1;
    }
    __syncthreads();                    // also fences the S reads above
    float pA0 = 0.f, pA1 = 0.f, pB0 = 0.f, pB1 = 0.f;
#pragma unroll
    for (int w = 0; w < 4; ++w) {
        if (wave > w) {
            pA0 += wv[0][w]; pA1 += wv[1][w];
            pB0 += wv[2][w]; pB1 += wv[3][w];
        }
    }
    vA0 += pA0; vA1 += pA1; vB0 += pB0; vB1 += pB1;
    // exclusive prefix: S[x] = sum_{idx<x}; S[NN] written by j==NN-1
    S0A[j + 1] = vA0; S1A[j + 1] = vA1;
    S0B[j + 1] = vB0; S1B[j + 1] = vB1;
    if (j == 0) { S0A[0] = 0.f; S1A[0] = 0.f; S0B[0] = 0.f; S1B[0] = 0.f; }
    __syncthreads();

    // ---- anchor contributions for (anchor a=j, rows i0 and i1) ----
    const float ta = mj.x;
    const int rlt_a = __float_as_int(mj.y), rle_a = __float_as_int(mj.z);
    const int eva   = evj;

    float lp = 0.f, np = 0.f;
#pragma unroll
    for (int r = 0; r < 2; ++r) {
        const float4 mi = (r == 0) ? smiA : smiB;
        const float* __restrict__ S0 = (r == 0) ? S0A : S0B;
        const float* __restrict__ S1 = (r == 0) ? S1A : S1B;
        const float lg = (r == 0) ? lgA : lgB;
        const int irow = (r == 0) ? i0 : i1;

        const float ti = mi.x;
        const int rlt_i = __float_as_int(mi.y), rle_i = __float_as_int(mi.z);
        const int evi   = __float_as_int(mi.w) >> 16;

        const int sgn = (ti > ta) ? 1 : ((ti < ta) ? -1 : 0);
        const unsigned pack = c_PACK[3 + sgn * (evi + 2 * eva)];
        const int rlo = min(rlt_i, rlt_a);
        const int rhi = max(rle_i, rle_a);

        const float q0lo = S0[rlo], q0hi = S0[rhi];
        const float q0a = S0[rlt_a], q0b = S0[rle_a], t0 = S0[NN];
        const float q1lo = S1[rlo], q1hi = S1[rhi];
        const float q1a = S1[rlt_a], q1b = S1[rle_a], t1 = S1[NN];

        const float LO0 = q0lo, HI0 = t0 - q0hi, MI0 = q0hi - q0lo - (q0b - q0a);
        const float LO1 = q1lo, HI1 = t1 - q1hi, MI1 = q1hi - q1lo - (q1b - q1a);

        const float c1 = (float)((pack >> 2) & 3u),  c2 = (float)((pack >> 4) & 3u);
        const float c3 = (float)((pack >> 6) & 3u),  c4 = (float)((pack >> 8) & 3u);
        const float c5 = (float)((pack >> 10) & 3u), c6 = (float)((pack >> 12) & 3u);

        float dx = c1 * LO0 + c2 * MI0 + c3 * HI0 + c4 * LO1 + c5 * MI1 + c6 * HI1;
        if (ti != ta) dx -= (float)((pack >> (2 * (2 + 3 * evi))) & 3u);  // j==i term

        if (irow != j && dx > 0.f) {
            lp += lg - logf(0.5f * dx);   // lg == L[row][a] == L[a][row]
            np += 1.f;
        }
    }
    if (np > 0.f) {
        atomicAdd(&accL[j], lp);
        atomicAdd(&accN[j], np);
    }

    // ---- last-block finalize (threadfence-reduction pattern) ----
    __threadfence();
    __syncthreads();
    if (j == 0) {
        const unsigned old = atomicAdd(ticket, 1u);
        s_done = (old == (NN / 2) - 1);
    }
    __syncthreads();
    if (!s_done) return;
    __threadfence();                    // acquire: see all blocks' atomics

    const float nj = accN[j];
    float lossj = (nj > 0.f) ? (-accL[j] / nj) : 0.f;
    float hasj  = (nj > 0.f) ? 1.f : 0.f;
#pragma unroll
    for (int off = 32; off > 0; off >>= 1) {
        lossj += __shfl_down(lossj, off);
        hasj  += __shfl_down(hasj, off);
    }
    if (lane == 0) { wv[0][wave] = lossj; wv[1][wave] = hasj; }
    __syncthreads();
    if (j == 0) {
        float tl = 0.f, th = 0.f;
#pragma unroll
        for (int w = 0; w < 5; ++w) { tl += wv[0][w]; th += wv[1][w]; }
        out[0] = tl / th;
    }
}

extern "C" void kernel_launch(void* const* d_in, const int* in_sizes, int n_in,
                              void* d_out, int out_size, void* d_ws, size_t ws_size,
                              hipStream_t stream) {
    const float* F  = (const float*)d_in[0];   // features (320,256) f32
    const float* yt = (const float*)d_in[1];   // y_times (320,) f32
    const int*   ye = (const int*)d_in[2];     // y_events (320,) i32
    float* out = (float*)d_out;
    float* ws  = (float*)d_ws;

    float4* meta = (float4*)ws;                        // 320 float4 (16B-aligned)
    float4* FT4  = (float4*)(ws + 4 * NN);             // 64*320 float4
    float*  acc  = ws + 4 * NN + 4 * (DD / 4) * NN;    // accL[320], accN[320], ticket

    prep_kernel<<<26, 256, 0, stream>>>(F, yt, ye, FT4, meta, acc);
    fused_kernel<<<NN / 2, NN, 0, stream>>>(F, FT4, meta, acc, out);
}